// Round 5
// baseline (296.779 us; speedup 1.0000x reference)
//
#include <hip/hip_runtime.h>
#include <stdint.h>
#include <math.h>

// Sizes
#define NN 512   // N_NODES
#define HID 64
#define LAT 256
#define TS 10
#define BAT 64

#define DEVFN static __device__ __forceinline__

DEVFN uint32_t rotl32(uint32_t v, int d) { return (v << d) | (v >> (32 - d)); }

// Threefry-2x32, 20 rounds (JAX threefry2x32_p). key=(k0,k1), count=(x0,x1).
DEVFN void threefry2x32(uint32_t k0, uint32_t k1, uint32_t x0, uint32_t x1,
                        uint32_t& o0, uint32_t& o1) {
  uint32_t ks0 = k0, ks1 = k1, ks2 = k0 ^ k1 ^ 0x1BD11BDAu;
  x0 += ks0; x1 += ks1;
  x0 += x1; x1 = rotl32(x1, 13); x1 ^= x0;
  x0 += x1; x1 = rotl32(x1, 15); x1 ^= x0;
  x0 += x1; x1 = rotl32(x1, 26); x1 ^= x0;
  x0 += x1; x1 = rotl32(x1, 6);  x1 ^= x0;
  x0 += ks1; x1 += ks2 + 1u;
  x0 += x1; x1 = rotl32(x1, 17); x1 ^= x0;
  x0 += x1; x1 = rotl32(x1, 29); x1 ^= x0;
  x0 += x1; x1 = rotl32(x1, 16); x1 ^= x0;
  x0 += x1; x1 = rotl32(x1, 24); x1 ^= x0;
  x0 += ks2; x1 += ks0 + 2u;
  x0 += x1; x1 = rotl32(x1, 13); x1 ^= x0;
  x0 += x1; x1 = rotl32(x1, 15); x1 ^= x0;
  x0 += x1; x1 = rotl32(x1, 26); x1 ^= x0;
  x0 += x1; x1 = rotl32(x1, 6);  x1 ^= x0;
  x0 += ks0; x1 += ks1 + 3u;
  x0 += x1; x1 = rotl32(x1, 17); x1 ^= x0;
  x0 += x1; x1 = rotl32(x1, 29); x1 ^= x0;
  x0 += x1; x1 = rotl32(x1, 16); x1 ^= x0;
  x0 += x1; x1 = rotl32(x1, 24); x1 ^= x0;
  x0 += ks1; x1 += ks2 + 4u;
  x0 += x1; x1 = rotl32(x1, 13); x1 ^= x0;
  x0 += x1; x1 = rotl32(x1, 15); x1 ^= x0;
  x0 += x1; x1 = rotl32(x1, 26); x1 ^= x0;
  x0 += x1; x1 = rotl32(x1, 6);  x1 ^= x0;
  x0 += ks2; x1 += ks0 + 5u;
  o0 = x0; o1 = x1;
}

DEVFN float sigmoidf_(float x) { return 1.0f / (1.0f + expf(-x)); }

// JAX gumbel from 32 random bits: uniform in [tiny, 1), g = -log(-log(u))
DEVFN float gumbel_bits(uint32_t bits) {
  const float tiny = 1.17549435e-38f;
  float f = __uint_as_float((bits >> 9) | 0x3F800000u) - 1.0f;
  float u = f * (1.0f - tiny) + tiny;
  u = fmaxf(tiny, u);
  return -logf(-logf(u));
}

// 256-thread block reduction (4 waves of 64)
DEVFN float block_red256(float v, float* red, bool ismax) {
  #pragma unroll
  for (int o = 32; o > 0; o >>= 1) {
    float w = __shfl_down(v, o, 64);
    v = ismax ? fmaxf(v, w) : v + w;
  }
  if ((threadIdx.x & 63) == 0) red[threadIdx.x >> 6] = v;
  __syncthreads();
  float r = ismax ? fmaxf(fmaxf(red[0], red[1]), fmaxf(red[2], red[3]))
                  : ((red[0] + red[1]) + (red[2] + red[3]));
  __syncthreads();
  return r;
}

// ---------------- wp1: x0[b*10+s][c] = X[b,s,:] @ wp1 + bp1 --------------------
// 160 blocks; each block 4 rows; group g = tid>>6 owns row, c = tid&63.
__global__ __launch_bounds__(256) void wp1_kernel(
    const float* __restrict__ X, const float* __restrict__ wp1,
    const float* __restrict__ bp1, float* __restrict__ x0) {
  const int r0 = blockIdx.x * 4;
  const int tid = threadIdx.x, g = tid >> 6, c = tid & 63;
  __shared__ float Xb[4][NN];
  for (int i = tid; i < 4 * NN; i += 256)
    Xb[i >> 9][i & 511] = X[r0 * NN + i];
  __syncthreads();
  float acc = bp1[c];
  for (int n = 0; n < NN; n++) acc += Xb[g][n] * wp1[n * HID + c];
  x0[(r0 + g) * HID + c] = acc;
}

// ---------------- encoder layers: one block per batch, 640 threads -------------
// thread = one (s,c) element; 10 waves deep for latency hiding.
__global__ __launch_bounds__(640) void enc2_kernel(
    const float* __restrict__ x0,
    const float* __restrict__ in_w, const float* __restrict__ in_b,
    const float* __restrict__ out_w, const float* __restrict__ out_b,
    const float* __restrict__ l1_w, const float* __restrict__ l1_b,
    const float* __restrict__ l2_w, const float* __restrict__ l2_b,
    const float* __restrict__ g1, const float* __restrict__ b1,
    const float* __restrict__ g2, const float* __restrict__ b2,
    float* __restrict__ x_enc) {
  const int b = blockIdx.x;
  const int tid = threadIdx.x;
  const int s = tid >> 6, c = tid & 63;
  __shared__ float xx[TS][HID];
  __shared__ float qkv[TS][192];
  __shared__ float sc[400];           // [h][r][t] flat
  __shared__ float tmpv[TS][HID];
  __shared__ float buf2[TS][HID];
  __shared__ float mu_s[TS], rs_s[TS];

  xx[s][c] = x0[b * 640 + tid];
  __syncthreads();

  for (int l = 0; l < 2; l++) {
    const float* inw = in_w + l * HID * 192; const float* inb = in_b + l * 192;
    const float* ow  = out_w + l * HID * HID; const float* ob = out_b + l * HID;
    const float* w1  = l1_w + l * HID * HID; const float* bb1 = l1_b + l * HID;
    const float* w2  = l2_w + l * HID * HID; const float* bb2 = l2_b + l * HID;
    const float* gg1 = g1 + l * HID; const float* be1 = b1 + l * HID;
    const float* gg2 = g2 + l * HID; const float* be2 = b2 + l * HID;

    // qkv = x @ in_w + in_b  (1920 outputs, 3 per thread)
    for (int o = tid; o < TS * 192; o += 640) {
      int ss = o / 192, cc = o % 192;
      float acc = inb[cc];
      for (int k = 0; k < HID; k++) acc += xx[ss][k] * inw[k * 192 + cc];
      qkv[ss][cc] = acc;
    }
    __syncthreads();
    // scores
    if (tid < 400) {
      int h = tid / 100, r = (tid / 10) % 10, t = tid % 10;
      float acc = 0.0f;
      for (int d = 0; d < 16; d++) acc += qkv[r][h * 16 + d] * qkv[t][64 + h * 16 + d];
      sc[tid] = acc * 0.25f;
    }
    __syncthreads();
    // softmax over t
    if (tid < 40) {
      int base = (tid / 10) * 100 + (tid % 10) * 10;
      float m = -1e30f;
      for (int t = 0; t < 10; t++) m = fmaxf(m, sc[base + t]);
      float e[10], sum = 0.0f;
      for (int t = 0; t < 10; t++) { e[t] = expf(sc[base + t] - m); sum += e[t]; }
      float inv = 1.0f / sum;
      for (int t = 0; t < 10; t++) sc[base + t] = e[t] * inv;
    }
    __syncthreads();
    // o = att @ v
    {
      const int h = c >> 4;
      float acc = 0.0f;
      for (int t = 0; t < 10; t++) acc += sc[h * 100 + s * 10 + t] * qkv[t][128 + c];
      tmpv[s][c] = acc;
    }
    __syncthreads();
    // proj + residual
    {
      float acc = ob[c] + xx[s][c];
      for (int k = 0; k < HID; k++) acc += tmpv[s][k] * ow[k * HID + c];
      buf2[s][c] = acc;
    }
    __syncthreads();
    // LN1 stats (serial per row, bitwise-stable order)
    if (tid < 10) {
      float m = 0.0f;
      for (int cc = 0; cc < HID; cc++) m += buf2[tid][cc];
      m *= (1.0f / 64.0f);
      float v = 0.0f;
      for (int cc = 0; cc < HID; cc++) { float d = buf2[tid][cc] - m; v += d * d; }
      v *= (1.0f / 64.0f);
      mu_s[tid] = m; rs_s[tid] = rsqrtf(v + 1e-5f);
    }
    __syncthreads();
    xx[s][c] = (buf2[s][c] - mu_s[s]) * rs_s[s] * gg1[c] + be1[c];
    __syncthreads();
    // FF1
    {
      float acc = bb1[c];
      for (int k = 0; k < HID; k++) acc += xx[s][k] * w1[k * HID + c];
      tmpv[s][c] = fmaxf(acc, 0.0f);
    }
    __syncthreads();
    // FF2 + residual
    {
      float acc = bb2[c] + xx[s][c];
      for (int k = 0; k < HID; k++) acc += tmpv[s][k] * w2[k * HID + c];
      buf2[s][c] = acc;
    }
    __syncthreads();
    // LN2 stats
    if (tid < 10) {
      float m = 0.0f;
      for (int cc = 0; cc < HID; cc++) m += buf2[tid][cc];
      m *= (1.0f / 64.0f);
      float v = 0.0f;
      for (int cc = 0; cc < HID; cc++) { float d = buf2[tid][cc] - m; v += d * d; }
      v *= (1.0f / 64.0f);
      mu_s[tid] = m; rs_s[tid] = rsqrtf(v + 1e-5f);
    }
    __syncthreads();
    xx[s][c] = (buf2[s][c] - mu_s[s]) * rs_s[s] * gg2[c] + be2[c];
    __syncthreads();
  }
  x_enc[b * 640 + tid] = xx[s][c];
}

// ---------------- wp2: x_inst / x_lag from x_enc -------------------------------
// 128 blocks: (b, half); thread owns output col n.
__global__ __launch_bounds__(256) void wp2_kernel(
    const float* __restrict__ x_enc, const float* __restrict__ wp2,
    const float* __restrict__ bp2,
    float* __restrict__ x_inst, float* __restrict__ x_lag) {
  const int b = blockIdx.x >> 1, half = blockIdx.x & 1;
  const int tid = threadIdx.x;
  const int n = half * 256 + tid;
  __shared__ float xxl[640];
  for (int i = tid; i < 640; i += 256) xxl[i] = x_enc[b * 640 + i];
  __syncthreads();
  float accs[10];
  #pragma unroll
  for (int si = 0; si < 10; si++) accs[si] = 0.0f;
  for (int k = 0; k < HID; k++) {
    float w = wp2[k * NN + n];
    #pragma unroll
    for (int si = 0; si < 10; si++) accs[si] += xxl[si * 64 + k] * w;
  }
  float bias = bp2[n];
  x_inst[b * NN + n] = accs[0] + bias;
  float lag = 0.0f;
  for (int si = 1; si < 10; si++) lag += accs[si];
  x_lag[b * NN + n] = lag * (1.0f / 9.0f) + bias;
}

// ---------------- adjacency: gram + gumbel + softmax + sigmoid -----------------
__global__ __launch_bounds__(256) void adj_kernel(
    const float* __restrict__ x_inst, const float* __restrict__ x_lag,
    const float* __restrict__ es_now, const float* __restrict__ es_lag,
    const float* __restrict__ prior, float* __restrict__ out) {
  const int k = blockIdx.x & 511;
  const int v = blockIdx.x >> 9;       // 0 = now, 1 = lag
  const int tid = threadIdx.x;
  const float* xs = v ? x_lag : x_inst;
  const float* es = v ? es_lag : es_now;
  __shared__ float ck[BAT];
  __shared__ float red[4];
  if (tid < BAT) ck[tid] = xs[tid * NN + k];
  __syncthreads();
  uint32_t ka, kb, t0, t1;
  threefry2x32(0u, 42u, 0u, (uint32_t)v, ka, kb);
  float vals[2];
  #pragma unroll
  for (int jj = 0; jj < 2; jj++) {
    int j = tid + jj * 256;
    float acc = 0.0f;
    for (int bb = 0; bb < BAT; bb++) acc += ck[bb] * xs[bb * NN + j];
    if (v) acc = sigmoidf_(acc);
    threefry2x32(ka, kb, 0u, (uint32_t)(k * NN + j), t0, t1);
    vals[jj] = acc + gumbel_bits(t0 ^ t1);
  }
  float m = block_red256(fmaxf(vals[0], vals[1]), red, true);
  float e0 = expf(vals[0] - m), e1 = expf(vals[1] - m);
  float s = block_red256(e0 + e1, red, false);
  float inv = 1.0f / s;
  #pragma unroll
  for (int jj = 0; jj < 2; jj++) {
    int j = tid + jj * 256;
    float a = (jj ? e1 : e0) * inv;
    float t = es[k * NN + j] + prior[k * NN + j] + a;
    float sg = sigmoidf_(t);
    sg = fminf(fmaxf(sg, 0.0f), 1.0f);
    if (j == k) sg = 0.0f;
    if (sg == 0.0f) sg = 1e-8f;
    out[v * NN * NN + k * NN + j] = sg;
  }
}

// ---------------- RealNVP flow ------------------------------------------------
__global__ __launch_bounds__(128) void flow_kernel(
    const float* __restrict__ Z, const float* __restrict__ fs_w, const float* __restrict__ fs_b,
    const float* __restrict__ ft_w, const float* __restrict__ ft_b, float* __restrict__ z2p) {
  const int n = blockIdx.x, c = threadIdx.x;
  __shared__ float z1[128];
  z1[c] = Z[n * LAT + c];
  __syncthreads();
  float a = fs_b[c], t = ft_b[c];
  for (int k = 0; k < 128; k++) {
    float zz = z1[k];
    a += zz * fs_w[k * 128 + c];
    t += zz * ft_w[k * 128 + c];
  }
  z2p[n * 128 + c] = sigmoidf_(a) * Z[n * LAT + 128 + c] + t;
}

// ---------------- gi table: only 100 distinct time values exist ----------------
__global__ __launch_bounds__(384) void gitab_kernel(
    const float* __restrict__ w_ih, const float* __restrict__ b_ih,
    float* __restrict__ gi_table) {
  const int v = blockIdx.x;      // 0..99
  const int t = threadIdx.x;     // col 0..383
  __shared__ float temb[256];
  if (t < 256) {
    float fr = (float)exp((double)(t & 127) * (10.0 / 127.0));  // np-style f64 -> f32
    float arg = (float)v * fr;
    temb[t] = (t < 128) ? sinf(arg) : cosf(arg);
  }
  __syncthreads();
  float acc = b_ih[t];
  for (int k = 0; k < 256; k++) acc += temb[k] * w_ih[k * 384 + t];
  gi_table[v * 384 + t] = acc;
}

// ---------------- GRU: w_hh register-resident, gi via table lookup -------------
__global__ __launch_bounds__(384) void gru_kernel2(
    const int* __restrict__ tctx, const float* __restrict__ w_hh,
    const float* __restrict__ b_hh, const float* __restrict__ gi_table,
    const float* __restrict__ tp_w, const float* __restrict__ tp_b,
    const float* __restrict__ z2p, float* __restrict__ z2f) {
  const int n = blockIdx.x, t = threadIdx.x;
  __shared__ float h[128];
  __shared__ float sums[256];   // gi+gh for r,z cols
  __shared__ float ghn[128];    // gh for n cols
  __shared__ float gin[128];    // gi for n cols
  float whh[128];
  #pragma unroll
  for (int k = 0; k < 128; k++) whh[k] = w_hh[k * 384 + t];
  float gis[10];
  #pragma unroll
  for (int s = 0; s < 10; s++) gis[s] = gi_table[tctx[n * 10 + s] * 384 + t];
  float tpw[10];
  #pragma unroll
  for (int s = 0; s < 10; s++) tpw[s] = tp_w[s];
  const float bhh = b_hh[t];
  if (t < 128) h[t] = 0.0f;
  float acc_tp = 0.0f;
  __syncthreads();
  #pragma unroll
  for (int s = 0; s < 10; s++) {
    float acc = bhh;
    const float4* h4 = (const float4*)h;
    #pragma unroll
    for (int k4 = 0; k4 < 32; k4++) {
      float4 hv = h4[k4];
      acc += hv.x * whh[4 * k4 + 0];
      acc += hv.y * whh[4 * k4 + 1];
      acc += hv.z * whh[4 * k4 + 2];
      acc += hv.w * whh[4 * k4 + 3];
    }
    if (t < 256) sums[t] = gis[s] + acc;
    else { ghn[t - 256] = acc; gin[t - 256] = gis[s]; }
    __syncthreads();
    if (t < 128) {
      float r = sigmoidf_(sums[t]);
      float z = sigmoidf_(sums[128 + t]);
      float nn2 = tanhf(gin[t] + r * ghn[t]);
      float hn = (1.0f - z) * nn2 + z * h[t];
      h[t] = hn;
      acc_tp += hn * tpw[s];
    }
    __syncthreads();
  }
  if (t < 128) z2f[n * 128 + t] = z2p[n * 128 + t] + acc_tp + tp_b[0];
}

// ---------------- Zn = concat(z1,z2f)@ltn + b; xl/xr = Zn@gat_w{l,r}+b ---------
__global__ __launch_bounds__(256) void zn_kernel(
    const float* __restrict__ Z, const float* __restrict__ z2f,
    const float* __restrict__ ltn_w, const float* __restrict__ ltn_b,
    const float* __restrict__ wl, const float* __restrict__ bl,
    const float* __restrict__ wr, const float* __restrict__ br,
    float* __restrict__ xl, float* __restrict__ xr) {
  const int n = blockIdx.x, tid = threadIdx.x;
  __shared__ float zrow[LAT];
  __shared__ float znrow[NN];
  if (tid < 128) { zrow[tid] = Z[n * LAT + tid]; zrow[128 + tid] = z2f[n * 128 + tid]; }
  __syncthreads();
  for (int o = tid; o < NN; o += 256) {
    float acc = ltn_b[o];
    for (int k = 0; k < LAT; k++) acc += zrow[k] * ltn_w[k * NN + o];
    znrow[o] = acc;
  }
  __syncthreads();
  {
    int o = tid;  // 256 cols
    float a = bl[o], bacc = br[o];
    for (int k = 0; k < NN; k++) {
      float z = znrow[k];
      a += z * wl[k * 256 + o];
      bacc += z * wr[k * 256 + o];
    }
    xl[n * 256 + o] = a;
    xr[n * 256 + o] = bacc;
  }
}

// ---------------- GATv2 attention: e, softmax, x_emb (one block per target i) --
// e stored [4][512]; x_emb j-parallel across waves with coalesced xl reads.
__global__ __launch_bounds__(256) void gat_kernel3(
    const float* __restrict__ xl, const float* __restrict__ xr,
    const float* __restrict__ attw, const float* __restrict__ gbias,
    float* __restrict__ xemb) {
  const int i = blockIdx.x, tid = threadIdx.x;
  __shared__ float xri[256];
  __shared__ float aw[256];
  __shared__ float e[4][NN];
  __shared__ float part[4][256];
  __shared__ float red[4];
  xri[tid] = xr[i * 256 + tid];
  aw[tid] = attw[tid];
  __syncthreads();
  // e[h][j] = sum_c leaky(xri[h*64+c] + xl[j][h*64+c]) * aw[h*64+c]
  #pragma unroll
  for (int jj = 0; jj < 2; jj++) {
    const int j = tid + jj * 256;
    const float4* xl4 = (const float4*)(xl + j * 256);
    #pragma unroll
    for (int hh = 0; hh < 4; hh++) {
      float acc = 0.0f;
      #pragma unroll 4
      for (int c4 = 0; c4 < 16; c4++) {
        float4 v = xl4[hh * 16 + c4];
        const int cb = hh * 64 + c4 * 4;
        float a0 = xri[cb + 0] + v.x; a0 = (a0 >= 0.0f) ? a0 : 0.2f * a0;
        float a1 = xri[cb + 1] + v.y; a1 = (a1 >= 0.0f) ? a1 : 0.2f * a1;
        float a2 = xri[cb + 2] + v.z; a2 = (a2 >= 0.0f) ? a2 : 0.2f * a2;
        float a3 = xri[cb + 3] + v.w; a3 = (a3 >= 0.0f) ? a3 : 0.2f * a3;
        acc += a0 * aw[cb + 0];
        acc += a1 * aw[cb + 1];
        acc += a2 * aw[cb + 2];
        acc += a3 * aw[cb + 3];
      }
      e[hh][j] = acc;
    }
  }
  __syncthreads();
  // softmax over j per head
  for (int hh = 0; hh < 4; hh++) {
    float v0 = e[hh][tid], v1 = e[hh][tid + 256];
    float m = block_red256(fmaxf(v0, v1), red, true);
    float e0 = expf(v0 - m), e1 = expf(v1 - m);
    float s = block_red256(e0 + e1, red, false);
    float inv = 1.0f / s;
    e[hh][tid] = e0 * inv;
    e[hh][tid + 256] = e1 * inv;
  }
  __syncthreads();
  // x_emb: wave w sums j in [w*128, w*128+128); acc[q] is output col q*64+lane
  {
    const int w = tid >> 6, lane = tid & 63;
    float acc0 = 0.0f, acc1 = 0.0f, acc2 = 0.0f, acc3 = 0.0f;
    const int j0 = w * 128;
    for (int j = j0; j < j0 + 128; j++) {
      const float* xlr = xl + j * 256 + lane;
      acc0 += e[0][j] * xlr[0];
      acc1 += e[1][j] * xlr[64];
      acc2 += e[2][j] * xlr[128];
      acc3 += e[3][j] * xlr[192];
    }
    part[w][lane]       = acc0;
    part[w][64 + lane]  = acc1;
    part[w][128 + lane] = acc2;
    part[w][192 + lane] = acc3;
  }
  __syncthreads();
  {
    float acc = ((part[0][tid] + part[1][tid]) + part[2][tid]) + part[3][tid];
    xemb[i * 256 + tid] = acc + gbias[tid];
  }
}

// ---------------- ml = x_emb @ gl_w + gl_b (tiled); mean/scale epilogue --------
__global__ __launch_bounds__(256) void glgemm_kernel(
    const float* __restrict__ xemb, const float* __restrict__ gl_w,
    const float* __restrict__ gl_b, float* __restrict__ out_mean,
    float* __restrict__ out_scale) {
  const int ct = blockIdx.x & 15, it = blockIdx.x >> 4;
  const int tid = threadIdx.x;
  const int i0 = it * 16, col = ct * 64 + (tid & 63), ti = tid >> 6;
  __shared__ float xe[16][LAT];   // 16KB
  for (int o = tid; o < 16 * LAT; o += 256) {
    xe[o >> 8][o & 255] = xemb[(i0 + (o >> 8)) * LAT + (o & 255)];
  }
  __syncthreads();
  const float bias = gl_b[col];
  float acc0 = bias, acc1 = bias, acc2 = bias, acc3 = bias;
  const int r0 = ti * 4;
  #pragma unroll 4
  for (int k = 0; k < LAT; k++) {
    float w = gl_w[k * 1024 + col];
    acc0 += xe[r0 + 0][k] * w;
    acc1 += xe[r0 + 1][k] * w;
    acc2 += xe[r0 + 2][k] * w;
    acc3 += xe[r0 + 3][k] * w;
  }
  float accs[4] = {acc0, acc1, acc2, acc3};
  if (col < 512) {
    #pragma unroll
    for (int q = 0; q < 4; q++) out_mean[(i0 + r0 + q) * NN + col] = accs[q];
  } else {
    #pragma unroll
    for (int q = 0; q < 4; q++) {
      float lv = fminf(fmaxf(accs[q], -5.0f), 2.0f);
      out_scale[(i0 + r0 + q) * NN + (col - 512)] = expf(0.5f * lv);
    }
  }
}

extern "C" void kernel_launch(void* const* d_in, const int* in_sizes, int n_in,
                              void* d_out, int out_size, void* d_ws, size_t ws_size,
                              hipStream_t stream) {
  (void)in_sizes; (void)n_in; (void)out_size; (void)ws_size;
  const float* X        = (const float*)d_in[0];
  const float* Z        = (const float*)d_in[1];
  const float* es_now   = (const float*)d_in[2];
  const float* es_lag   = (const float*)d_in[3];
  const float* prior    = (const float*)d_in[4];
  const float* wp1      = (const float*)d_in[5];
  const float* bp1      = (const float*)d_in[6];
  const float* enc_in_w = (const float*)d_in[7];
  const float* enc_in_b = (const float*)d_in[8];
  const float* enc_out_w= (const float*)d_in[9];
  const float* enc_out_b= (const float*)d_in[10];
  const float* enc_l1_w = (const float*)d_in[11];
  const float* enc_l1_b = (const float*)d_in[12];
  const float* enc_l2_w = (const float*)d_in[13];
  const float* enc_l2_b = (const float*)d_in[14];
  const float* enc_g1   = (const float*)d_in[15];
  const float* enc_b1   = (const float*)d_in[16];
  const float* enc_g2   = (const float*)d_in[17];
  const float* enc_b2   = (const float*)d_in[18];
  const float* wp2      = (const float*)d_in[19];
  const float* bp2      = (const float*)d_in[20];
  const float* fs_w     = (const float*)d_in[21];
  const float* fs_b     = (const float*)d_in[22];
  const float* ft_w     = (const float*)d_in[23];
  const float* ft_b     = (const float*)d_in[24];
  const float* gru_w_ih = (const float*)d_in[25];
  const float* gru_w_hh = (const float*)d_in[26];
  const float* gru_b_ih = (const float*)d_in[27];
  const float* gru_b_hh = (const float*)d_in[28];
  const float* tp_w     = (const float*)d_in[29];
  const float* tp_b     = (const float*)d_in[30];
  const float* ltn_w    = (const float*)d_in[31];
  const float* ltn_b    = (const float*)d_in[32];
  const float* gat_wl   = (const float*)d_in[33];
  const float* gat_bl   = (const float*)d_in[34];
  const float* gat_wr   = (const float*)d_in[35];
  const float* gat_br   = (const float*)d_in[36];
  const float* gat_att  = (const float*)d_in[37];
  const float* gat_bias = (const float*)d_in[38];
  const float* gl_w     = (const float*)d_in[39];
  const float* gl_b     = (const float*)d_in[40];
  const int*   tctx     = (const int*)d_in[41];

  float* out = (float*)d_out;
  float* ws  = (float*)d_ws;
  // ws layout (floats)
  float* x_inst   = ws;                // 64*512
  float* x_lag    = ws + 32768;        // 64*512
  float* z2p      = ws + 65536;        // 512*128
  float* z2f      = ws + 131072;       // 512*128
  float* xl       = ws + 196608;       // 512*256
  float* xr       = ws + 327680;       // 512*256
  float* gi_table = ws + 458752;       // 100*384
  float* xemb     = ws + 497152;       // 512*256
  float* x0       = ws + 628224;       // 640*64
  float* x_enc    = ws + 669184;       // 640*64

  wp1_kernel<<<dim3(160), dim3(256), 0, stream>>>(X, wp1, bp1, x0);
  enc2_kernel<<<dim3(BAT), dim3(640), 0, stream>>>(
      x0, enc_in_w, enc_in_b, enc_out_w, enc_out_b,
      enc_l1_w, enc_l1_b, enc_l2_w, enc_l2_b,
      enc_g1, enc_b1, enc_g2, enc_b2, x_enc);
  wp2_kernel<<<dim3(128), dim3(256), 0, stream>>>(x_enc, wp2, bp2, x_inst, x_lag);
  adj_kernel<<<dim3(2 * NN), dim3(256), 0, stream>>>(
      x_inst, x_lag, es_now, es_lag, prior, out);
  gitab_kernel<<<dim3(100), dim3(384), 0, stream>>>(gru_w_ih, gru_b_ih, gi_table);
  flow_kernel<<<dim3(NN), dim3(128), 0, stream>>>(Z, fs_w, fs_b, ft_w, ft_b, z2p);
  gru_kernel2<<<dim3(NN), dim3(384), 0, stream>>>(
      tctx, gru_w_hh, gru_b_hh, gi_table, tp_w, tp_b, z2p, z2f);
  zn_kernel<<<dim3(NN), dim3(256), 0, stream>>>(
      Z, z2f, ltn_w, ltn_b, gat_wl, gat_bl, gat_wr, gat_br, xl, xr);
  gat_kernel3<<<dim3(NN), dim3(256), 0, stream>>>(
      xl, xr, gat_att, gat_bias, xemb);
  glgemm_kernel<<<dim3(512), dim3(256), 0, stream>>>(
      xemb, gl_w, gl_b, out + 2 * NN * NN, out + 3 * NN * NN);
}

// Round 6
// 237.695 us; speedup vs baseline: 1.2486x; 1.2486x over previous
//
#include <hip/hip_runtime.h>
#include <stdint.h>
#include <math.h>

// Sizes
#define NN 512   // N_NODES
#define HID 64
#define LAT 256
#define TS 10
#define BAT 64

#define DEVFN static __device__ __forceinline__

DEVFN uint32_t rotl32(uint32_t v, int d) { return (v << d) | (v >> (32 - d)); }

// Threefry-2x32, 20 rounds (JAX threefry2x32_p). key=(k0,k1), count=(x0,x1).
DEVFN void threefry2x32(uint32_t k0, uint32_t k1, uint32_t x0, uint32_t x1,
                        uint32_t& o0, uint32_t& o1) {
  uint32_t ks0 = k0, ks1 = k1, ks2 = k0 ^ k1 ^ 0x1BD11BDAu;
  x0 += ks0; x1 += ks1;
  x0 += x1; x1 = rotl32(x1, 13); x1 ^= x0;
  x0 += x1; x1 = rotl32(x1, 15); x1 ^= x0;
  x0 += x1; x1 = rotl32(x1, 26); x1 ^= x0;
  x0 += x1; x1 = rotl32(x1, 6);  x1 ^= x0;
  x0 += ks1; x1 += ks2 + 1u;
  x0 += x1; x1 = rotl32(x1, 17); x1 ^= x0;
  x0 += x1; x1 = rotl32(x1, 29); x1 ^= x0;
  x0 += x1; x1 = rotl32(x1, 16); x1 ^= x0;
  x0 += x1; x1 = rotl32(x1, 24); x1 ^= x0;
  x0 += ks2; x1 += ks0 + 2u;
  x0 += x1; x1 = rotl32(x1, 13); x1 ^= x0;
  x0 += x1; x1 = rotl32(x1, 15); x1 ^= x0;
  x0 += x1; x1 = rotl32(x1, 26); x1 ^= x0;
  x0 += x1; x1 = rotl32(x1, 6);  x1 ^= x0;
  x0 += ks0; x1 += ks1 + 3u;
  x0 += x1; x1 = rotl32(x1, 17); x1 ^= x0;
  x0 += x1; x1 = rotl32(x1, 29); x1 ^= x0;
  x0 += x1; x1 = rotl32(x1, 16); x1 ^= x0;
  x0 += x1; x1 = rotl32(x1, 24); x1 ^= x0;
  x0 += ks1; x1 += ks2 + 4u;
  x0 += x1; x1 = rotl32(x1, 13); x1 ^= x0;
  x0 += x1; x1 = rotl32(x1, 15); x1 ^= x0;
  x0 += x1; x1 = rotl32(x1, 26); x1 ^= x0;
  x0 += x1; x1 = rotl32(x1, 6);  x1 ^= x0;
  x0 += ks2; x1 += ks0 + 5u;
  o0 = x0; o1 = x1;
}

DEVFN float sigmoidf_(float x) { return 1.0f / (1.0f + expf(-x)); }

// JAX gumbel from 32 random bits: uniform in [tiny, 1), g = -log(-log(u))
DEVFN float gumbel_bits(uint32_t bits) {
  const float tiny = 1.17549435e-38f;
  float f = __uint_as_float((bits >> 9) | 0x3F800000u) - 1.0f;
  float u = f * (1.0f - tiny) + tiny;
  u = fmaxf(tiny, u);
  return -logf(-logf(u));
}

// 256-thread block reduction (4 waves of 64)
DEVFN float block_red256(float v, float* red, bool ismax) {
  #pragma unroll
  for (int o = 32; o > 0; o >>= 1) {
    float w = __shfl_down(v, o, 64);
    v = ismax ? fmaxf(v, w) : v + w;
  }
  if ((threadIdx.x & 63) == 0) red[threadIdx.x >> 6] = v;
  __syncthreads();
  float r = ismax ? fmaxf(fmaxf(red[0], red[1]), fmaxf(red[2], red[3]))
                  : ((red[0] + red[1]) + (red[2] + red[3]));
  __syncthreads();
  return r;
}

// ---------------- wp1: x0[row][c] = X[row,:] @ wp1 + bp1 (W chunks in LDS) -----
__global__ __launch_bounds__(256) void wp1_kernel(
    const float* __restrict__ X, const float* __restrict__ wp1,
    const float* __restrict__ bp1, float* __restrict__ x0) {
  const int r0 = blockIdx.x * 4;
  const int tid = threadIdx.x, g = tid >> 6, c = tid & 63;
  __shared__ float Xb[4][NN];      // 8KB
  __shared__ float Wb[128 * 64];   // 32KB
  for (int i = tid; i < 4 * NN; i += 256)
    Xb[i >> 9][i & 511] = X[r0 * NN + i];
  float acc = bp1[c];
  for (int ch = 0; ch < 4; ch++) {
    const int n0 = ch * 128;
    __syncthreads();
    for (int i = tid; i < 128 * 64; i += 256) Wb[i] = wp1[n0 * 64 + i];
    __syncthreads();
    #pragma unroll 8
    for (int n = 0; n < 128; n++) acc += Xb[g][n0 + n] * Wb[n * 64 + c];
  }
  x0[(r0 + g) * HID + c] = acc;
}

// ---------------- encoder layers: one block per batch, weights LDS-staged ------
__global__ __launch_bounds__(640) void enc3_kernel(
    const float* __restrict__ x0,
    const float* __restrict__ in_w, const float* __restrict__ in_b,
    const float* __restrict__ out_w, const float* __restrict__ out_b,
    const float* __restrict__ l1_w, const float* __restrict__ l1_b,
    const float* __restrict__ l2_w, const float* __restrict__ l2_b,
    const float* __restrict__ g1, const float* __restrict__ b1,
    const float* __restrict__ g2, const float* __restrict__ b2,
    float* __restrict__ x_enc) {
  const int b = blockIdx.x;
  const int tid = threadIdx.x;
  const int s = tid >> 6, c = tid & 63;
  __shared__ float Wb[64 * 96];       // 24KB reusable weight buffer
  __shared__ float xx[TS][HID];
  __shared__ float qkv[TS][192];
  __shared__ float scb[400];
  __shared__ float tmpv[TS][HID];
  __shared__ float buf2[TS][HID];
  __shared__ float mu_s[TS], rs_s[TS];

  xx[s][c] = x0[b * 640 + tid];

  for (int l = 0; l < 2; l++) {
    const float* inw = in_w + l * HID * 192; const float* inb = in_b + l * 192;
    const float* ow  = out_w + l * HID * HID; const float* ob = out_b + l * HID;
    const float* w1  = l1_w + l * HID * HID; const float* bb1 = l1_b + l * HID;
    const float* w2  = l2_w + l * HID * HID; const float* bb2 = l2_b + l * HID;
    const float* gg1 = g1 + l * HID; const float* be1 = b1 + l * HID;
    const float* gg2 = g2 + l * HID; const float* be2 = b2 + l * HID;

    // qkv = x @ in_w + in_b, in two 96-col halves with W half in LDS
    for (int half = 0; half < 2; half++) {
      const int c0 = half * 96;
      __syncthreads();   // xx ready (first) / Wb free (later)
      for (int i = tid; i < 64 * 96; i += 640)
        Wb[i] = inw[(i / 96) * 192 + c0 + (i % 96)];
      __syncthreads();
      for (int o = tid; o < TS * 96; o += 640) {
        int ss = o / 96, cc = o % 96;
        float acc = inb[c0 + cc];
        for (int k = 0; k < HID; k++) acc += xx[ss][k] * Wb[k * 96 + cc];
        qkv[ss][c0 + cc] = acc;
      }
    }
    __syncthreads();
    // scores (tid<400) + stage out_w into Wb concurrently
    for (int i = tid; i < 64 * 64; i += 640) Wb[i] = ow[i];
    if (tid < 400) {
      int h = tid / 100, r = (tid / 10) % 10, t = tid % 10;
      float acc = 0.0f;
      for (int d = 0; d < 16; d++) acc += qkv[r][h * 16 + d] * qkv[t][64 + h * 16 + d];
      scb[tid] = acc * 0.25f;
    }
    __syncthreads();
    // softmax over t
    if (tid < 40) {
      int base = (tid / 10) * 100 + (tid % 10) * 10;
      float m = -1e30f;
      for (int t = 0; t < 10; t++) m = fmaxf(m, scb[base + t]);
      float e[10], sum = 0.0f;
      for (int t = 0; t < 10; t++) { e[t] = expf(scb[base + t] - m); sum += e[t]; }
      float inv = 1.0f / sum;
      for (int t = 0; t < 10; t++) scb[base + t] = e[t] * inv;
    }
    __syncthreads();
    // o = att @ v
    {
      const int h = c >> 4;
      float acc = 0.0f;
      for (int t = 0; t < 10; t++) acc += scb[h * 100 + s * 10 + t] * qkv[t][128 + c];
      tmpv[s][c] = acc;
    }
    __syncthreads();
    // proj + residual (Wb = out_w)
    {
      float acc = ob[c] + xx[s][c];
      for (int k = 0; k < HID; k++) acc += tmpv[s][k] * Wb[k * HID + c];
      buf2[s][c] = acc;
    }
    __syncthreads();
    // LN1 stats (tid<10, bitwise order) + stage l1_w
    for (int i = tid; i < 64 * 64; i += 640) Wb[i] = w1[i];
    if (tid < 10) {
      float m = 0.0f;
      for (int cc = 0; cc < HID; cc++) m += buf2[tid][cc];
      m *= (1.0f / 64.0f);
      float v = 0.0f;
      for (int cc = 0; cc < HID; cc++) { float d = buf2[tid][cc] - m; v += d * d; }
      v *= (1.0f / 64.0f);
      mu_s[tid] = m; rs_s[tid] = rsqrtf(v + 1e-5f);
    }
    __syncthreads();
    xx[s][c] = (buf2[s][c] - mu_s[s]) * rs_s[s] * gg1[c] + be1[c];
    __syncthreads();
    // FF1 (Wb = l1_w)
    {
      float acc = bb1[c];
      for (int k = 0; k < HID; k++) acc += xx[s][k] * Wb[k * HID + c];
      tmpv[s][c] = fmaxf(acc, 0.0f);
    }
    __syncthreads();
    // stage l2_w
    for (int i = tid; i < 64 * 64; i += 640) Wb[i] = w2[i];
    __syncthreads();
    // FF2 + residual (Wb = l2_w)
    {
      float acc = bb2[c] + xx[s][c];
      for (int k = 0; k < HID; k++) acc += tmpv[s][k] * Wb[k * HID + c];
      buf2[s][c] = acc;
    }
    __syncthreads();
    // LN2 stats
    if (tid < 10) {
      float m = 0.0f;
      for (int cc = 0; cc < HID; cc++) m += buf2[tid][cc];
      m *= (1.0f / 64.0f);
      float v = 0.0f;
      for (int cc = 0; cc < HID; cc++) { float d = buf2[tid][cc] - m; v += d * d; }
      v *= (1.0f / 64.0f);
      mu_s[tid] = m; rs_s[tid] = rsqrtf(v + 1e-5f);
    }
    __syncthreads();
    xx[s][c] = (buf2[s][c] - mu_s[s]) * rs_s[s] * gg2[c] + be2[c];
  }
  x_enc[b * 640 + tid] = xx[s][c];
}

// ---------------- wp2: x_inst / x_lag from x_enc (W chunks in LDS) -------------
__global__ __launch_bounds__(256) void wp2_kernel(
    const float* __restrict__ x_enc, const float* __restrict__ wp2,
    const float* __restrict__ bp2,
    float* __restrict__ x_inst, float* __restrict__ x_lag) {
  const int b = blockIdx.x >> 1, half = blockIdx.x & 1;
  const int tid = threadIdx.x;
  const int n = half * 256 + tid;
  __shared__ float xxl[640];
  __shared__ float Wb[32 * 256];   // 32KB
  for (int i = tid; i < 640; i += 256) xxl[i] = x_enc[b * 640 + i];
  float accs[10];
  #pragma unroll
  for (int si = 0; si < 10; si++) accs[si] = 0.0f;
  for (int ch = 0; ch < 2; ch++) {
    __syncthreads();
    for (int i = tid; i < 32 * 256; i += 256)
      Wb[i] = wp2[(ch * 32 + (i >> 8)) * NN + half * 256 + (i & 255)];
    __syncthreads();
    for (int k = 0; k < 32; k++) {
      float w = Wb[k * 256 + tid];
      #pragma unroll
      for (int si = 0; si < 10; si++) accs[si] += xxl[si * 64 + ch * 32 + k] * w;
    }
  }
  float bias = bp2[n];
  x_inst[b * NN + n] = accs[0] + bias;
  float lag = 0.0f;
  for (int si = 1; si < 10; si++) lag += accs[si];
  x_lag[b * NN + n] = lag * (1.0f / 9.0f) + bias;
}

// ---------------- adjacency: gram + gumbel + softmax + sigmoid -----------------
__global__ __launch_bounds__(256) void adj_kernel(
    const float* __restrict__ x_inst, const float* __restrict__ x_lag,
    const float* __restrict__ es_now, const float* __restrict__ es_lag,
    const float* __restrict__ prior, float* __restrict__ out) {
  const int k = blockIdx.x & 511;
  const int v = blockIdx.x >> 9;       // 0 = now, 1 = lag
  const int tid = threadIdx.x;
  const float* xs = v ? x_lag : x_inst;
  const float* es = v ? es_lag : es_now;
  __shared__ float ck[BAT];
  __shared__ float red[4];
  if (tid < BAT) ck[tid] = xs[tid * NN + k];
  __syncthreads();
  uint32_t ka, kb, t0, t1;
  threefry2x32(0u, 42u, 0u, (uint32_t)v, ka, kb);
  float vals[2];
  #pragma unroll
  for (int jj = 0; jj < 2; jj++) {
    int j = tid + jj * 256;
    float acc = 0.0f;
    for (int bb = 0; bb < BAT; bb++) acc += ck[bb] * xs[bb * NN + j];
    if (v) acc = sigmoidf_(acc);
    threefry2x32(ka, kb, 0u, (uint32_t)(k * NN + j), t0, t1);
    vals[jj] = acc + gumbel_bits(t0 ^ t1);
  }
  float m = block_red256(fmaxf(vals[0], vals[1]), red, true);
  float e0 = expf(vals[0] - m), e1 = expf(vals[1] - m);
  float s = block_red256(e0 + e1, red, false);
  float inv = 1.0f / s;
  #pragma unroll
  for (int jj = 0; jj < 2; jj++) {
    int j = tid + jj * 256;
    float a = (jj ? e1 : e0) * inv;
    float t = es[k * NN + j] + prior[k * NN + j] + a;
    float sg = sigmoidf_(t);
    sg = fminf(fmaxf(sg, 0.0f), 1.0f);
    if (j == k) sg = 0.0f;
    if (sg == 0.0f) sg = 1e-8f;
    out[v * NN * NN + k * NN + j] = sg;
  }
}

// ---------------- RealNVP flow ------------------------------------------------
__global__ __launch_bounds__(128) void flow_kernel(
    const float* __restrict__ Z, const float* __restrict__ fs_w, const float* __restrict__ fs_b,
    const float* __restrict__ ft_w, const float* __restrict__ ft_b, float* __restrict__ z2p) {
  const int n = blockIdx.x, c = threadIdx.x;
  __shared__ float z1[128];
  z1[c] = Z[n * LAT + c];
  __syncthreads();
  float a = fs_b[c], t = ft_b[c];
  for (int k = 0; k < 128; k++) {
    float zz = z1[k];
    a += zz * fs_w[k * 128 + c];
    t += zz * ft_w[k * 128 + c];
  }
  z2p[n * 128 + c] = sigmoidf_(a) * Z[n * LAT + 128 + c] + t;
}

// ---------------- gi table: only 100 distinct time values exist ----------------
__global__ __launch_bounds__(384) void gitab_kernel(
    const float* __restrict__ w_ih, const float* __restrict__ b_ih,
    float* __restrict__ gi_table) {
  const int v = blockIdx.x;      // 0..99
  const int t = threadIdx.x;     // col 0..383
  __shared__ float temb[256];
  if (t < 256) {
    float fr = (float)exp((double)(t & 127) * (10.0 / 127.0));  // np-style f64 -> f32
    float arg = (float)v * fr;
    temb[t] = (t < 128) ? sinf(arg) : cosf(arg);
  }
  __syncthreads();
  float acc = b_ih[t];
  for (int k = 0; k < 256; k++) acc += temb[k] * w_ih[k * 384 + t];
  gi_table[v * 384 + t] = acc;
}

// ---------------- GRU: w_hh register-resident, gi via table lookup -------------
__global__ __launch_bounds__(384) void gru_kernel2(
    const int* __restrict__ tctx, const float* __restrict__ w_hh,
    const float* __restrict__ b_hh, const float* __restrict__ gi_table,
    const float* __restrict__ tp_w, const float* __restrict__ tp_b,
    const float* __restrict__ z2p, float* __restrict__ z2f) {
  const int n = blockIdx.x, t = threadIdx.x;
  __shared__ float h[128];
  __shared__ float sums[256];   // gi+gh for r,z cols
  __shared__ float ghn[128];    // gh for n cols
  __shared__ float gin[128];    // gi for n cols
  float whh[128];
  #pragma unroll
  for (int k = 0; k < 128; k++) whh[k] = w_hh[k * 384 + t];
  float gis[10];
  #pragma unroll
  for (int s = 0; s < 10; s++) gis[s] = gi_table[tctx[n * 10 + s] * 384 + t];
  float tpw[10];
  #pragma unroll
  for (int s = 0; s < 10; s++) tpw[s] = tp_w[s];
  const float bhh = b_hh[t];
  if (t < 128) h[t] = 0.0f;
  float acc_tp = 0.0f;
  __syncthreads();
  #pragma unroll
  for (int s = 0; s < 10; s++) {
    float acc = bhh;
    const float4* h4 = (const float4*)h;
    #pragma unroll
    for (int k4 = 0; k4 < 32; k4++) {
      float4 hv = h4[k4];
      acc += hv.x * whh[4 * k4 + 0];
      acc += hv.y * whh[4 * k4 + 1];
      acc += hv.z * whh[4 * k4 + 2];
      acc += hv.w * whh[4 * k4 + 3];
    }
    if (t < 256) sums[t] = gis[s] + acc;
    else { ghn[t - 256] = acc; gin[t - 256] = gis[s]; }
    __syncthreads();
    if (t < 128) {
      float r = sigmoidf_(sums[t]);
      float z = sigmoidf_(sums[128 + t]);
      float nn2 = tanhf(gin[t] + r * ghn[t]);
      float hn = (1.0f - z) * nn2 + z * h[t];
      h[t] = hn;
      acc_tp += hn * tpw[s];
    }
    __syncthreads();
  }
  if (t < 128) z2f[n * 128 + t] = z2p[n * 128 + t] + acc_tp + tp_b[0];
}

// ---------------- Zn = concat(z1,z2f)@ltn + b; xl/xr = Zn@gat_w{l,r}+b ---------
__global__ __launch_bounds__(256) void zn_kernel(
    const float* __restrict__ Z, const float* __restrict__ z2f,
    const float* __restrict__ ltn_w, const float* __restrict__ ltn_b,
    const float* __restrict__ wl, const float* __restrict__ bl,
    const float* __restrict__ wr, const float* __restrict__ br,
    float* __restrict__ xl, float* __restrict__ xr) {
  const int n = blockIdx.x, tid = threadIdx.x;
  __shared__ float zrow[LAT];
  __shared__ float znrow[NN];
  if (tid < 128) { zrow[tid] = Z[n * LAT + tid]; zrow[128 + tid] = z2f[n * 128 + tid]; }
  __syncthreads();
  for (int o = tid; o < NN; o += 256) {
    float acc = ltn_b[o];
    for (int k = 0; k < LAT; k++) acc += zrow[k] * ltn_w[k * NN + o];
    znrow[o] = acc;
  }
  __syncthreads();
  {
    int o = tid;  // 256 cols
    float a = bl[o], bacc = br[o];
    for (int k = 0; k < NN; k++) {
      float z = znrow[k];
      a += z * wl[k * 256 + o];
      bacc += z * wr[k * 256 + o];
    }
    xl[n * 256 + o] = a;
    xr[n * 256 + o] = bacc;
  }
}

// ---------------- GATv2 attention: e, softmax, x_emb (one block per target i) --
__global__ __launch_bounds__(256) void gat_kernel3(
    const float* __restrict__ xl, const float* __restrict__ xr,
    const float* __restrict__ attw, const float* __restrict__ gbias,
    float* __restrict__ xemb) {
  const int i = blockIdx.x, tid = threadIdx.x;
  __shared__ float xri[256];
  __shared__ float aw[256];
  __shared__ float e[4][NN];
  __shared__ float part[4][256];
  __shared__ float red[4];
  xri[tid] = xr[i * 256 + tid];
  aw[tid] = attw[tid];
  __syncthreads();
  // e[h][j] = sum_c leaky(xri[h*64+c] + xl[j][h*64+c]) * aw[h*64+c]
  #pragma unroll
  for (int jj = 0; jj < 2; jj++) {
    const int j = tid + jj * 256;
    const float4* xl4 = (const float4*)(xl + j * 256);
    #pragma unroll
    for (int hh = 0; hh < 4; hh++) {
      float acc = 0.0f;
      #pragma unroll 4
      for (int c4 = 0; c4 < 16; c4++) {
        float4 v = xl4[hh * 16 + c4];
        const int cb = hh * 64 + c4 * 4;
        float a0 = xri[cb + 0] + v.x; a0 = (a0 >= 0.0f) ? a0 : 0.2f * a0;
        float a1 = xri[cb + 1] + v.y; a1 = (a1 >= 0.0f) ? a1 : 0.2f * a1;
        float a2 = xri[cb + 2] + v.z; a2 = (a2 >= 0.0f) ? a2 : 0.2f * a2;
        float a3 = xri[cb + 3] + v.w; a3 = (a3 >= 0.0f) ? a3 : 0.2f * a3;
        acc += a0 * aw[cb + 0];
        acc += a1 * aw[cb + 1];
        acc += a2 * aw[cb + 2];
        acc += a3 * aw[cb + 3];
      }
      e[hh][j] = acc;
    }
  }
  __syncthreads();
  // softmax over j per head
  for (int hh = 0; hh < 4; hh++) {
    float v0 = e[hh][tid], v1 = e[hh][tid + 256];
    float m = block_red256(fmaxf(v0, v1), red, true);
    float e0 = expf(v0 - m), e1 = expf(v1 - m);
    float s = block_red256(e0 + e1, red, false);
    float inv = 1.0f / s;
    e[hh][tid] = e0 * inv;
    e[hh][tid + 256] = e1 * inv;
  }
  __syncthreads();
  // x_emb: wave w sums j in [w*128, w*128+128); coalesced xl reads
  {
    const int w = tid >> 6, lane = tid & 63;
    float acc0 = 0.0f, acc1 = 0.0f, acc2 = 0.0f, acc3 = 0.0f;
    const int j0 = w * 128;
    for (int j = j0; j < j0 + 128; j++) {
      const float* xlr = xl + j * 256 + lane;
      acc0 += e[0][j] * xlr[0];
      acc1 += e[1][j] * xlr[64];
      acc2 += e[2][j] * xlr[128];
      acc3 += e[3][j] * xlr[192];
    }
    part[w][lane]       = acc0;
    part[w][64 + lane]  = acc1;
    part[w][128 + lane] = acc2;
    part[w][192 + lane] = acc3;
  }
  __syncthreads();
  {
    float acc = ((part[0][tid] + part[1][tid]) + part[2][tid]) + part[3][tid];
    xemb[i * 256 + tid] = acc + gbias[tid];
  }
}

// ---------------- ml = x_emb @ gl_w + gl_b (tiled); mean/scale epilogue --------
__global__ __launch_bounds__(256) void glgemm_kernel(
    const float* __restrict__ xemb, const float* __restrict__ gl_w,
    const float* __restrict__ gl_b, float* __restrict__ out_mean,
    float* __restrict__ out_scale) {
  const int ct = blockIdx.x & 15, it = blockIdx.x >> 4;
  const int tid = threadIdx.x;
  const int i0 = it * 16, col = ct * 64 + (tid & 63), ti = tid >> 6;
  __shared__ float xe[16][LAT];   // 16KB
  for (int o = tid; o < 16 * LAT; o += 256) {
    xe[o >> 8][o & 255] = xemb[(i0 + (o >> 8)) * LAT + (o & 255)];
  }
  __syncthreads();
  const float bias = gl_b[col];
  float acc0 = bias, acc1 = bias, acc2 = bias, acc3 = bias;
  const int r0 = ti * 4;
  #pragma unroll 4
  for (int k = 0; k < LAT; k++) {
    float w = gl_w[k * 1024 + col];
    acc0 += xe[r0 + 0][k] * w;
    acc1 += xe[r0 + 1][k] * w;
    acc2 += xe[r0 + 2][k] * w;
    acc3 += xe[r0 + 3][k] * w;
  }
  float accs[4] = {acc0, acc1, acc2, acc3};
  if (col < 512) {
    #pragma unroll
    for (int q = 0; q < 4; q++) out_mean[(i0 + r0 + q) * NN + col] = accs[q];
  } else {
    #pragma unroll
    for (int q = 0; q < 4; q++) {
      float lv = fminf(fmaxf(accs[q], -5.0f), 2.0f);
      out_scale[(i0 + r0 + q) * NN + (col - 512)] = expf(0.5f * lv);
    }
  }
}

extern "C" void kernel_launch(void* const* d_in, const int* in_sizes, int n_in,
                              void* d_out, int out_size, void* d_ws, size_t ws_size,
                              hipStream_t stream) {
  (void)in_sizes; (void)n_in; (void)out_size; (void)ws_size;
  const float* X        = (const float*)d_in[0];
  const float* Z        = (const float*)d_in[1];
  const float* es_now   = (const float*)d_in[2];
  const float* es_lag   = (const float*)d_in[3];
  const float* prior    = (const float*)d_in[4];
  const float* wp1      = (const float*)d_in[5];
  const float* bp1      = (const float*)d_in[6];
  const float* enc_in_w = (const float*)d_in[7];
  const float* enc_in_b = (const float*)d_in[8];
  const float* enc_out_w= (const float*)d_in[9];
  const float* enc_out_b= (const float*)d_in[10];
  const float* enc_l1_w = (const float*)d_in[11];
  const float* enc_l1_b = (const float*)d_in[12];
  const float* enc_l2_w = (const float*)d_in[13];
  const float* enc_l2_b = (const float*)d_in[14];
  const float* enc_g1   = (const float*)d_in[15];
  const float* enc_b1   = (const float*)d_in[16];
  const float* enc_g2   = (const float*)d_in[17];
  const float* enc_b2   = (const float*)d_in[18];
  const float* wp2      = (const float*)d_in[19];
  const float* bp2      = (const float*)d_in[20];
  const float* fs_w     = (const float*)d_in[21];
  const float* fs_b     = (const float*)d_in[22];
  const float* ft_w     = (const float*)d_in[23];
  const float* ft_b     = (const float*)d_in[24];
  const float* gru_w_ih = (const float*)d_in[25];
  const float* gru_w_hh = (const float*)d_in[26];
  const float* gru_b_ih = (const float*)d_in[27];
  const float* gru_b_hh = (const float*)d_in[28];
  const float* tp_w     = (const float*)d_in[29];
  const float* tp_b     = (const float*)d_in[30];
  const float* ltn_w    = (const float*)d_in[31];
  const float* ltn_b    = (const float*)d_in[32];
  const float* gat_wl   = (const float*)d_in[33];
  const float* gat_bl   = (const float*)d_in[34];
  const float* gat_wr   = (const float*)d_in[35];
  const float* gat_br   = (const float*)d_in[36];
  const float* gat_att  = (const float*)d_in[37];
  const float* gat_bias = (const float*)d_in[38];
  const float* gl_w     = (const float*)d_in[39];
  const float* gl_b     = (const float*)d_in[40];
  const int*   tctx     = (const int*)d_in[41];

  float* out = (float*)d_out;
  float* ws  = (float*)d_ws;
  // ws layout (floats)
  float* x_inst   = ws;                // 64*512
  float* x_lag    = ws + 32768;        // 64*512
  float* z2p      = ws + 65536;        // 512*128
  float* z2f      = ws + 131072;       // 512*128
  float* xl       = ws + 196608;       // 512*256
  float* xr       = ws + 327680;       // 512*256
  float* gi_table = ws + 458752;       // 100*384
  float* xemb     = ws + 497152;       // 512*256
  float* x0       = ws + 628224;       // 640*64
  float* x_enc    = ws + 669184;       // 640*64

  wp1_kernel<<<dim3(160), dim3(256), 0, stream>>>(X, wp1, bp1, x0);
  enc3_kernel<<<dim3(BAT), dim3(640), 0, stream>>>(
      x0, enc_in_w, enc_in_b, enc_out_w, enc_out_b,
      enc_l1_w, enc_l1_b, enc_l2_w, enc_l2_b,
      enc_g1, enc_b1, enc_g2, enc_b2, x_enc);
  wp2_kernel<<<dim3(128), dim3(256), 0, stream>>>(x_enc, wp2, bp2, x_inst, x_lag);
  adj_kernel<<<dim3(2 * NN), dim3(256), 0, stream>>>(
      x_inst, x_lag, es_now, es_lag, prior, out);
  gitab_kernel<<<dim3(100), dim3(384), 0, stream>>>(gru_w_ih, gru_b_ih, gi_table);
  flow_kernel<<<dim3(NN), dim3(128), 0, stream>>>(Z, fs_w, fs_b, ft_w, ft_b, z2p);
  gru_kernel2<<<dim3(NN), dim3(384), 0, stream>>>(
      tctx, gru_w_hh, gru_b_hh, gi_table, tp_w, tp_b, z2p, z2f);
  zn_kernel<<<dim3(NN), dim3(256), 0, stream>>>(
      Z, z2f, ltn_w, ltn_b, gat_wl, gat_bl, gat_wr, gat_br, xl, xr);
  gat_kernel3<<<dim3(NN), dim3(256), 0, stream>>>(
      xl, xr, gat_att, gat_bias, xemb);
  glgemm_kernel<<<dim3(512), dim3(256), 0, stream>>>(
      xemb, gl_w, gl_b, out + 2 * NN * NN, out + 3 * NN * NN);
}

// Round 7
// 218.218 us; speedup vs baseline: 1.3600x; 1.0893x over previous
//
#include <hip/hip_runtime.h>
#include <stdint.h>
#include <math.h>

// Sizes
#define NN 512   // N_NODES
#define HID 64
#define LAT 256
#define TS 10
#define BAT 64

#define DEVFN static __device__ __forceinline__

DEVFN uint32_t rotl32(uint32_t v, int d) { return (v << d) | (v >> (32 - d)); }

// Threefry-2x32, 20 rounds (JAX threefry2x32_p). key=(k0,k1), count=(x0,x1).
DEVFN void threefry2x32(uint32_t k0, uint32_t k1, uint32_t x0, uint32_t x1,
                        uint32_t& o0, uint32_t& o1) {
  uint32_t ks0 = k0, ks1 = k1, ks2 = k0 ^ k1 ^ 0x1BD11BDAu;
  x0 += ks0; x1 += ks1;
  x0 += x1; x1 = rotl32(x1, 13); x1 ^= x0;
  x0 += x1; x1 = rotl32(x1, 15); x1 ^= x0;
  x0 += x1; x1 = rotl32(x1, 26); x1 ^= x0;
  x0 += x1; x1 = rotl32(x1, 6);  x1 ^= x0;
  x0 += ks1; x1 += ks2 + 1u;
  x0 += x1; x1 = rotl32(x1, 17); x1 ^= x0;
  x0 += x1; x1 = rotl32(x1, 29); x1 ^= x0;
  x0 += x1; x1 = rotl32(x1, 16); x1 ^= x0;
  x0 += x1; x1 = rotl32(x1, 24); x1 ^= x0;
  x0 += ks2; x1 += ks0 + 2u;
  x0 += x1; x1 = rotl32(x1, 13); x1 ^= x0;
  x0 += x1; x1 = rotl32(x1, 15); x1 ^= x0;
  x0 += x1; x1 = rotl32(x1, 26); x1 ^= x0;
  x0 += x1; x1 = rotl32(x1, 6);  x1 ^= x0;
  x0 += ks0; x1 += ks1 + 3u;
  x0 += x1; x1 = rotl32(x1, 17); x1 ^= x0;
  x0 += x1; x1 = rotl32(x1, 29); x1 ^= x0;
  x0 += x1; x1 = rotl32(x1, 16); x1 ^= x0;
  x0 += x1; x1 = rotl32(x1, 24); x1 ^= x0;
  x0 += ks1; x1 += ks2 + 4u;
  x0 += x1; x1 = rotl32(x1, 13); x1 ^= x0;
  x0 += x1; x1 = rotl32(x1, 15); x1 ^= x0;
  x0 += x1; x1 = rotl32(x1, 26); x1 ^= x0;
  x0 += x1; x1 = rotl32(x1, 6);  x1 ^= x0;
  x0 += ks2; x1 += ks0 + 5u;
  o0 = x0; o1 = x1;
}

DEVFN float sigmoidf_(float x) { return 1.0f / (1.0f + expf(-x)); }

// JAX gumbel from 32 random bits: uniform in [tiny, 1), g = -log(-log(u))
DEVFN float gumbel_bits(uint32_t bits) {
  const float tiny = 1.17549435e-38f;
  float f = __uint_as_float((bits >> 9) | 0x3F800000u) - 1.0f;
  float u = f * (1.0f - tiny) + tiny;
  u = fmaxf(tiny, u);
  return -logf(-logf(u));
}

// 256-thread block reduction (4 waves of 64)
DEVFN float block_red256(float v, float* red, bool ismax) {
  #pragma unroll
  for (int o = 32; o > 0; o >>= 1) {
    float w = __shfl_down(v, o, 64);
    v = ismax ? fmaxf(v, w) : v + w;
  }
  if ((threadIdx.x & 63) == 0) red[threadIdx.x >> 6] = v;
  __syncthreads();
  float r = ismax ? fmaxf(fmaxf(red[0], red[1]), fmaxf(red[2], red[3]))
                  : ((red[0] + red[1]) + (red[2] + red[3]));
  __syncthreads();
  return r;
}

// float4 dot-step, k-ascending order preserved
#define ACC4(acc, x4, w4) { acc += (x4).x * (w4).x; acc += (x4).y * (w4).y; \
                            acc += (x4).z * (w4).z; acc += (x4).w * (w4).w; }

// ---------------- wp1: x0 = X @ wp1 + bp1 (float4 k-chunk LDS) -----------------
__global__ __launch_bounds__(256) void wp1_kernel(
    const float* __restrict__ X, const float* __restrict__ wp1,
    const float* __restrict__ bp1, float* __restrict__ x0) {
  const int r0 = blockIdx.x * 4;
  const int tid = threadIdx.x, g = tid >> 6, c = tid & 63;
  __shared__ float Xb[4][NN];      // 8KB
  __shared__ float Wb[128 * 64];   // 32KB, k-chunk float4 layout
  for (int i = tid; i < 4 * NN; i += 256)
    Xb[i >> 9][i & 511] = X[r0 * NN + i];
  float acc = bp1[c];
  for (int ch = 0; ch < 4; ch++) {
    const int n0 = ch * 128;
    __syncthreads();
    for (int i = tid; i < 128 * 64; i += 256) {
      int k = i >> 6, cc = i & 63;
      Wb[((k >> 2) * 64 + cc) * 4 + (k & 3)] = wp1[(n0 + k) * 64 + cc];
    }
    __syncthreads();
    #pragma unroll 8
    for (int n4 = 0; n4 < 32; n4++) {
      float4 w4 = *(const float4*)&Wb[(n4 * 64 + c) * 4];
      float4 x4 = *(const float4*)&Xb[g][n0 + n4 * 4];
      ACC4(acc, x4, w4);
    }
  }
  x0[(r0 + g) * HID + c] = acc;
}

// ---------------- encoder layers: all weights LDS float4-staged per layer ------
__global__ __launch_bounds__(640) void enc4_kernel(
    const float* __restrict__ x0,
    const float* __restrict__ in_w, const float* __restrict__ in_b,
    const float* __restrict__ out_w, const float* __restrict__ out_b,
    const float* __restrict__ l1_w, const float* __restrict__ l1_b,
    const float* __restrict__ l2_w, const float* __restrict__ l2_b,
    const float* __restrict__ g1, const float* __restrict__ b1,
    const float* __restrict__ g2, const float* __restrict__ b2,
    float* __restrict__ x_enc) {
  const int b = blockIdx.x;
  const int tid = threadIdx.x;
  const int s = tid >> 6, c = tid & 63;
  __shared__ float WbA[12288];        // 48KB: in_w, k-chunk f4 (ncol=192)
  __shared__ float WbB[12288];        // 48KB: out_w|l1_w|l2_w, k-chunk f4 (ncol=64)
  __shared__ float xx[TS][HID];
  __shared__ float qkv[TS][192];
  __shared__ float scb[400];
  __shared__ float tmpv[TS][HID];
  __shared__ float buf2[TS][HID];
  __shared__ float mu_s[TS], rs_s[TS];

  xx[s][c] = x0[b * 640 + tid];

  for (int l = 0; l < 2; l++) {
    const float* inw = in_w + l * HID * 192; const float* inb = in_b + l * 192;
    const float* ow  = out_w + l * HID * HID; const float* ob = out_b + l * HID;
    const float* w1  = l1_w + l * HID * HID; const float* bb1 = l1_b + l * HID;
    const float* w2  = l2_w + l * HID * HID; const float* bb2 = l2_b + l * HID;
    const float* gg1 = g1 + l * HID; const float* be1 = b1 + l * HID;
    const float* gg2 = g2 + l * HID; const float* be2 = b2 + l * HID;

    __syncthreads();   // xx ready / prev-layer reads of Wb done
    // stage in_w -> WbA (k-chunk float4, ncol=192)
    for (int i = tid; i < 12288; i += 640) {
      int k = i / 192, cc = i % 192;
      WbA[((k >> 2) * 192 + cc) * 4 + (k & 3)] = inw[i];
    }
    // stage out_w, l1_w, l2_w -> WbB (ncol=64)
    for (int i = tid; i < 12288; i += 640) {
      int m = i >> 12, rem = i & 4095, k = rem >> 6, cc = rem & 63;
      float v = (m == 0) ? ow[rem] : (m == 1) ? w1[rem] : w2[rem];
      WbB[m * 4096 + ((k >> 2) * 64 + cc) * 4 + (k & 3)] = v;
    }
    __syncthreads();

    // qkv = x @ in_w + in_b (1920 outputs, 3/thread)
    for (int o = tid; o < TS * 192; o += 640) {
      int ss = o / 192, cc = o % 192;
      float acc = inb[cc];
      #pragma unroll
      for (int k4 = 0; k4 < 16; k4++) {
        float4 w4 = *(const float4*)&WbA[(k4 * 192 + cc) * 4];
        float4 x4 = *(const float4*)&xx[ss][k4 * 4];
        ACC4(acc, x4, w4);
      }
      qkv[ss][cc] = acc;
    }
    __syncthreads();
    // scores
    if (tid < 400) {
      int h = tid / 100, r = (tid / 10) % 10, t = tid % 10;
      float acc = 0.0f;
      for (int d = 0; d < 16; d++) acc += qkv[r][h * 16 + d] * qkv[t][64 + h * 16 + d];
      scb[tid] = acc * 0.25f;
    }
    __syncthreads();
    // softmax over t
    if (tid < 40) {
      int base = (tid / 10) * 100 + (tid % 10) * 10;
      float m = -1e30f;
      for (int t = 0; t < 10; t++) m = fmaxf(m, scb[base + t]);
      float e[10], sum = 0.0f;
      for (int t = 0; t < 10; t++) { e[t] = expf(scb[base + t] - m); sum += e[t]; }
      float inv = 1.0f / sum;
      for (int t = 0; t < 10; t++) scb[base + t] = e[t] * inv;
    }
    __syncthreads();
    // o = att @ v
    {
      const int h = c >> 4;
      float acc = 0.0f;
      for (int t = 0; t < 10; t++) acc += scb[h * 100 + s * 10 + t] * qkv[t][128 + c];
      tmpv[s][c] = acc;
    }
    __syncthreads();
    // proj + residual (WbB m=0)
    {
      float acc = ob[c] + xx[s][c];
      #pragma unroll
      for (int k4 = 0; k4 < 16; k4++) {
        float4 w4 = *(const float4*)&WbB[(k4 * 64 + c) * 4];
        float4 x4 = *(const float4*)&tmpv[s][k4 * 4];
        ACC4(acc, x4, w4);
      }
      buf2[s][c] = acc;
    }
    __syncthreads();
    // LN1 stats (bitwise order)
    if (tid < 10) {
      float m = 0.0f;
      for (int cc = 0; cc < HID; cc++) m += buf2[tid][cc];
      m *= (1.0f / 64.0f);
      float v = 0.0f;
      for (int cc = 0; cc < HID; cc++) { float d = buf2[tid][cc] - m; v += d * d; }
      v *= (1.0f / 64.0f);
      mu_s[tid] = m; rs_s[tid] = rsqrtf(v + 1e-5f);
    }
    __syncthreads();
    xx[s][c] = (buf2[s][c] - mu_s[s]) * rs_s[s] * gg1[c] + be1[c];
    __syncthreads();
    // FF1 (WbB m=1)
    {
      float acc = bb1[c];
      #pragma unroll
      for (int k4 = 0; k4 < 16; k4++) {
        float4 w4 = *(const float4*)&WbB[4096 + (k4 * 64 + c) * 4];
        float4 x4 = *(const float4*)&xx[s][k4 * 4];
        ACC4(acc, x4, w4);
      }
      tmpv[s][c] = fmaxf(acc, 0.0f);
    }
    __syncthreads();
    // FF2 + residual (WbB m=2)
    {
      float acc = bb2[c] + xx[s][c];
      #pragma unroll
      for (int k4 = 0; k4 < 16; k4++) {
        float4 w4 = *(const float4*)&WbB[8192 + (k4 * 64 + c) * 4];
        float4 x4 = *(const float4*)&tmpv[s][k4 * 4];
        ACC4(acc, x4, w4);
      }
      buf2[s][c] = acc;
    }
    __syncthreads();
    // LN2 stats
    if (tid < 10) {
      float m = 0.0f;
      for (int cc = 0; cc < HID; cc++) m += buf2[tid][cc];
      m *= (1.0f / 64.0f);
      float v = 0.0f;
      for (int cc = 0; cc < HID; cc++) { float d = buf2[tid][cc] - m; v += d * d; }
      v *= (1.0f / 64.0f);
      mu_s[tid] = m; rs_s[tid] = rsqrtf(v + 1e-5f);
    }
    __syncthreads();
    xx[s][c] = (buf2[s][c] - mu_s[s]) * rs_s[s] * gg2[c] + be2[c];
  }
  __syncthreads();
  x_enc[b * 640 + tid] = xx[s][c];
}

// ---------------- wp2: x_inst / x_lag from x_enc (W chunks in LDS) -------------
__global__ __launch_bounds__(256) void wp2_kernel(
    const float* __restrict__ x_enc, const float* __restrict__ wp2,
    const float* __restrict__ bp2,
    float* __restrict__ x_inst, float* __restrict__ x_lag) {
  const int b = blockIdx.x >> 1, half = blockIdx.x & 1;
  const int tid = threadIdx.x;
  const int n = half * 256 + tid;
  __shared__ float xxl[640];
  __shared__ float Wb[32 * 256];   // 32KB
  for (int i = tid; i < 640; i += 256) xxl[i] = x_enc[b * 640 + i];
  float accs[10];
  #pragma unroll
  for (int si = 0; si < 10; si++) accs[si] = 0.0f;
  for (int ch = 0; ch < 2; ch++) {
    __syncthreads();
    for (int i = tid; i < 32 * 256; i += 256)
      Wb[i] = wp2[(ch * 32 + (i >> 8)) * NN + half * 256 + (i & 255)];
    __syncthreads();
    for (int k = 0; k < 32; k++) {
      float w = Wb[k * 256 + tid];
      #pragma unroll
      for (int si = 0; si < 10; si++) accs[si] += xxl[si * 64 + ch * 32 + k] * w;
    }
  }
  float bias = bp2[n];
  x_inst[b * NN + n] = accs[0] + bias;
  float lag = 0.0f;
  for (int si = 1; si < 10; si++) lag += accs[si];
  x_lag[b * NN + n] = lag * (1.0f / 9.0f) + bias;
}

// ---------------- adjacency: gram + gumbel + softmax + sigmoid -----------------
__global__ __launch_bounds__(256) void adj_kernel(
    const float* __restrict__ x_inst, const float* __restrict__ x_lag,
    const float* __restrict__ es_now, const float* __restrict__ es_lag,
    const float* __restrict__ prior, float* __restrict__ out) {
  const int k = blockIdx.x & 511;
  const int v = blockIdx.x >> 9;       // 0 = now, 1 = lag
  const int tid = threadIdx.x;
  const float* xs = v ? x_lag : x_inst;
  const float* es = v ? es_lag : es_now;
  __shared__ float ck[BAT];
  __shared__ float red[4];
  if (tid < BAT) ck[tid] = xs[tid * NN + k];
  __syncthreads();
  uint32_t ka, kb, t0, t1;
  threefry2x32(0u, 42u, 0u, (uint32_t)v, ka, kb);
  float vals[2];
  #pragma unroll
  for (int jj = 0; jj < 2; jj++) {
    int j = tid + jj * 256;
    float acc = 0.0f;
    for (int bb = 0; bb < BAT; bb++) acc += ck[bb] * xs[bb * NN + j];
    if (v) acc = sigmoidf_(acc);
    threefry2x32(ka, kb, 0u, (uint32_t)(k * NN + j), t0, t1);
    vals[jj] = acc + gumbel_bits(t0 ^ t1);
  }
  float m = block_red256(fmaxf(vals[0], vals[1]), red, true);
  float e0 = expf(vals[0] - m), e1 = expf(vals[1] - m);
  float s = block_red256(e0 + e1, red, false);
  float inv = 1.0f / s;
  #pragma unroll
  for (int jj = 0; jj < 2; jj++) {
    int j = tid + jj * 256;
    float a = (jj ? e1 : e0) * inv;
    float t = es[k * NN + j] + prior[k * NN + j] + a;
    float sg = sigmoidf_(t);
    sg = fminf(fmaxf(sg, 0.0f), 1.0f);
    if (j == k) sg = 0.0f;
    if (sg == 0.0f) sg = 1e-8f;
    out[v * NN * NN + k * NN + j] = sg;
  }
}

// ---------------- RealNVP flow ------------------------------------------------
__global__ __launch_bounds__(128) void flow_kernel(
    const float* __restrict__ Z, const float* __restrict__ fs_w, const float* __restrict__ fs_b,
    const float* __restrict__ ft_w, const float* __restrict__ ft_b, float* __restrict__ z2p) {
  const int n = blockIdx.x, c = threadIdx.x;
  __shared__ float z1[128];
  z1[c] = Z[n * LAT + c];
  __syncthreads();
  float a = fs_b[c], t = ft_b[c];
  for (int k = 0; k < 128; k++) {
    float zz = z1[k];
    a += zz * fs_w[k * 128 + c];
    t += zz * ft_w[k * 128 + c];
  }
  z2p[n * 128 + c] = sigmoidf_(a) * Z[n * LAT + 128 + c] + t;
}

// ---------------- gi table: only 100 distinct time values exist ----------------
__global__ __launch_bounds__(384) void gitab_kernel(
    const float* __restrict__ w_ih, const float* __restrict__ b_ih,
    float* __restrict__ gi_table) {
  const int v = blockIdx.x;      // 0..99
  const int t = threadIdx.x;     // col 0..383
  __shared__ float temb[256];
  if (t < 256) {
    float fr = (float)exp((double)(t & 127) * (10.0 / 127.0));  // np-style f64 -> f32
    float arg = (float)v * fr;
    temb[t] = (t < 128) ? sinf(arg) : cosf(arg);
  }
  __syncthreads();
  float acc = b_ih[t];
  for (int k = 0; k < 256; k++) acc += temb[k] * w_ih[k * 384 + t];
  gi_table[v * 384 + t] = acc;
}

// ---------------- GRU: w_hh register-resident, gi via table lookup -------------
__global__ __launch_bounds__(384) void gru_kernel2(
    const int* __restrict__ tctx, const float* __restrict__ w_hh,
    const float* __restrict__ b_hh, const float* __restrict__ gi_table,
    const float* __restrict__ tp_w, const float* __restrict__ tp_b,
    const float* __restrict__ z2p, float* __restrict__ z2f) {
  const int n = blockIdx.x, t = threadIdx.x;
  __shared__ float h[128];
  __shared__ float sums[256];   // gi+gh for r,z cols
  __shared__ float ghn[128];    // gh for n cols
  __shared__ float gin[128];    // gi for n cols
  float whh[128];
  #pragma unroll
  for (int k = 0; k < 128; k++) whh[k] = w_hh[k * 384 + t];
  float gis[10];
  #pragma unroll
  for (int s = 0; s < 10; s++) gis[s] = gi_table[tctx[n * 10 + s] * 384 + t];
  float tpw[10];
  #pragma unroll
  for (int s = 0; s < 10; s++) tpw[s] = tp_w[s];
  const float bhh = b_hh[t];
  if (t < 128) h[t] = 0.0f;
  float acc_tp = 0.0f;
  __syncthreads();
  #pragma unroll
  for (int s = 0; s < 10; s++) {
    float acc = bhh;
    const float4* h4 = (const float4*)h;
    #pragma unroll
    for (int k4 = 0; k4 < 32; k4++) {
      float4 hv = h4[k4];
      acc += hv.x * whh[4 * k4 + 0];
      acc += hv.y * whh[4 * k4 + 1];
      acc += hv.z * whh[4 * k4 + 2];
      acc += hv.w * whh[4 * k4 + 3];
    }
    if (t < 256) sums[t] = gis[s] + acc;
    else { ghn[t - 256] = acc; gin[t - 256] = gis[s]; }
    __syncthreads();
    if (t < 128) {
      float r = sigmoidf_(sums[t]);
      float z = sigmoidf_(sums[128 + t]);
      float nn2 = tanhf(gin[t] + r * ghn[t]);
      float hn = (1.0f - z) * nn2 + z * h[t];
      h[t] = hn;
      acc_tp += hn * tpw[s];
    }
    __syncthreads();
  }
  if (t < 128) z2f[n * 128 + t] = z2p[n * 128 + t] + acc_tp + tp_b[0];
}

// ---------------- znA: zn_ws = concat(z1,z2f) @ ltn_w + b (4 nodes/block) ------
// grid 512 = 128 ntiles x 4 colgroups; thread: col o, two nodes (g, g+2).
__global__ __launch_bounds__(256) void znA_kernel(
    const float* __restrict__ Z, const float* __restrict__ z2f,
    const float* __restrict__ ltn_w, const float* __restrict__ ltn_b,
    float* __restrict__ zn_ws) {
  const int nt = blockIdx.x >> 2, cg = blockIdx.x & 3;
  const int tid = threadIdx.x;
  const int oo = tid & 127, gsel = tid >> 7;
  const int o = cg * 128 + oo;
  const int n0 = nt * 4;
  __shared__ float zcat[4][LAT];   // 4KB
  for (int i = tid; i < 4 * LAT; i += 256) {
    int g = i >> 8, k = i & 255;
    zcat[g][k] = (k < 128) ? Z[(n0 + g) * LAT + k] : z2f[(n0 + g) * 128 + (k - 128)];
  }
  __syncthreads();
  const float bias = ltn_b[o];
  float accA = bias, accB = bias;
  const int g0 = gsel, g1 = gsel + 2;
  for (int k = 0; k < LAT; k++) {
    float w = ltn_w[k * NN + o];
    accA += zcat[g0][k] * w;
    accB += zcat[g1][k] * w;
  }
  zn_ws[(n0 + g0) * NN + o] = accA;
  zn_ws[(n0 + g1) * NN + o] = accB;
}

// ---------------- znB: xl/xr = zn_ws @ gat_w{l,r} + b (4 nodes/block) ----------
// grid 512 = 128 ntiles x 4 colgroups of 64; thread: (node g, col o).
__global__ __launch_bounds__(256) void znB_kernel(
    const float* __restrict__ zn_ws,
    const float* __restrict__ wl, const float* __restrict__ bl,
    const float* __restrict__ wr, const float* __restrict__ br,
    float* __restrict__ xl, float* __restrict__ xr) {
  const int nt = blockIdx.x >> 2, cg = blockIdx.x & 3;
  const int tid = threadIdx.x;
  const int o = cg * 64 + (tid & 63), g = tid >> 6;
  const int n = nt * 4 + g;
  __shared__ float znr[4][NN];   // 8KB
  for (int i = tid; i < 4 * NN; i += 256)
    znr[i >> 9][i & 511] = zn_ws[(nt * 4 + (i >> 9)) * NN + (i & 511)];
  __syncthreads();
  float accL = bl[o], accR = br[o];
  for (int k = 0; k < NN; k++) {
    float z = znr[g][k];
    accL += z * wl[k * 256 + o];
    accR += z * wr[k * 256 + o];
  }
  xl[n * 256 + o] = accL;
  xr[n * 256 + o] = accR;
}

// ---------------- GATv2 attention: e, softmax, x_emb (one block per target i) --
__global__ __launch_bounds__(256) void gat_kernel3(
    const float* __restrict__ xl, const float* __restrict__ xr,
    const float* __restrict__ attw, const float* __restrict__ gbias,
    float* __restrict__ xemb) {
  const int i = blockIdx.x, tid = threadIdx.x;
  __shared__ float xri[256];
  __shared__ float aw[256];
  __shared__ float e[4][NN];
  __shared__ float part[4][256];
  __shared__ float red[4];
  xri[tid] = xr[i * 256 + tid];
  aw[tid] = attw[tid];
  __syncthreads();
  // e[h][j] = sum_c leaky(xri[h*64+c] + xl[j][h*64+c]) * aw[h*64+c]
  #pragma unroll
  for (int jj = 0; jj < 2; jj++) {
    const int j = tid + jj * 256;
    const float4* xl4 = (const float4*)(xl + j * 256);
    #pragma unroll
    for (int hh = 0; hh < 4; hh++) {
      float acc = 0.0f;
      #pragma unroll 4
      for (int c4 = 0; c4 < 16; c4++) {
        float4 v = xl4[hh * 16 + c4];
        const int cb = hh * 64 + c4 * 4;
        float a0 = xri[cb + 0] + v.x; a0 = (a0 >= 0.0f) ? a0 : 0.2f * a0;
        float a1 = xri[cb + 1] + v.y; a1 = (a1 >= 0.0f) ? a1 : 0.2f * a1;
        float a2 = xri[cb + 2] + v.z; a2 = (a2 >= 0.0f) ? a2 : 0.2f * a2;
        float a3 = xri[cb + 3] + v.w; a3 = (a3 >= 0.0f) ? a3 : 0.2f * a3;
        acc += a0 * aw[cb + 0];
        acc += a1 * aw[cb + 1];
        acc += a2 * aw[cb + 2];
        acc += a3 * aw[cb + 3];
      }
      e[hh][j] = acc;
    }
  }
  __syncthreads();
  // softmax over j per head
  for (int hh = 0; hh < 4; hh++) {
    float v0 = e[hh][tid], v1 = e[hh][tid + 256];
    float m = block_red256(fmaxf(v0, v1), red, true);
    float e0 = expf(v0 - m), e1 = expf(v1 - m);
    float s = block_red256(e0 + e1, red, false);
    float inv = 1.0f / s;
    e[hh][tid] = e0 * inv;
    e[hh][tid + 256] = e1 * inv;
  }
  __syncthreads();
  // x_emb: wave w sums j in [w*128, w*128+128); coalesced xl reads
  {
    const int w = tid >> 6, lane = tid & 63;
    float acc0 = 0.0f, acc1 = 0.0f, acc2 = 0.0f, acc3 = 0.0f;
    const int j0 = w * 128;
    for (int j = j0; j < j0 + 128; j++) {
      const float* xlr = xl + j * 256 + lane;
      acc0 += e[0][j] * xlr[0];
      acc1 += e[1][j] * xlr[64];
      acc2 += e[2][j] * xlr[128];
      acc3 += e[3][j] * xlr[192];
    }
    part[w][lane]       = acc0;
    part[w][64 + lane]  = acc1;
    part[w][128 + lane] = acc2;
    part[w][192 + lane] = acc3;
  }
  __syncthreads();
  {
    float acc = ((part[0][tid] + part[1][tid]) + part[2][tid]) + part[3][tid];
    xemb[i * 256 + tid] = acc + gbias[tid];
  }
}

// ---------------- ml = x_emb @ gl_w + gl_b (tiled); mean/scale epilogue --------
__global__ __launch_bounds__(256) void glgemm_kernel(
    const float* __restrict__ xemb, const float* __restrict__ gl_w,
    const float* __restrict__ gl_b, float* __restrict__ out_mean,
    float* __restrict__ out_scale) {
  const int ct = blockIdx.x & 15, it = blockIdx.x >> 4;
  const int tid = threadIdx.x;
  const int i0 = it * 16, col = ct * 64 + (tid & 63), ti = tid >> 6;
  __shared__ float xe[16][LAT];   // 16KB
  for (int o = tid; o < 16 * LAT; o += 256) {
    xe[o >> 8][o & 255] = xemb[(i0 + (o >> 8)) * LAT + (o & 255)];
  }
  __syncthreads();
  const float bias = gl_b[col];
  float acc0 = bias, acc1 = bias, acc2 = bias, acc3 = bias;
  const int r0 = ti * 4;
  #pragma unroll 4
  for (int k = 0; k < LAT; k++) {
    float w = gl_w[k * 1024 + col];
    acc0 += xe[r0 + 0][k] * w;
    acc1 += xe[r0 + 1][k] * w;
    acc2 += xe[r0 + 2][k] * w;
    acc3 += xe[r0 + 3][k] * w;
  }
  float accs[4] = {acc0, acc1, acc2, acc3};
  if (col < 512) {
    #pragma unroll
    for (int q = 0; q < 4; q++) out_mean[(i0 + r0 + q) * NN + col] = accs[q];
  } else {
    #pragma unroll
    for (int q = 0; q < 4; q++) {
      float lv = fminf(fmaxf(accs[q], -5.0f), 2.0f);
      out_scale[(i0 + r0 + q) * NN + (col - 512)] = expf(0.5f * lv);
    }
  }
}

extern "C" void kernel_launch(void* const* d_in, const int* in_sizes, int n_in,
                              void* d_out, int out_size, void* d_ws, size_t ws_size,
                              hipStream_t stream) {
  (void)in_sizes; (void)n_in; (void)out_size; (void)ws_size;
  const float* X        = (const float*)d_in[0];
  const float* Z        = (const float*)d_in[1];
  const float* es_now   = (const float*)d_in[2];
  const float* es_lag   = (const float*)d_in[3];
  const float* prior    = (const float*)d_in[4];
  const float* wp1      = (const float*)d_in[5];
  const float* bp1      = (const float*)d_in[6];
  const float* enc_in_w = (const float*)d_in[7];
  const float* enc_in_b = (const float*)d_in[8];
  const float* enc_out_w= (const float*)d_in[9];
  const float* enc_out_b= (const float*)d_in[10];
  const float* enc_l1_w = (const float*)d_in[11];
  const float* enc_l1_b = (const float*)d_in[12];
  const float* enc_l2_w = (const float*)d_in[13];
  const float* enc_l2_b = (const float*)d_in[14];
  const float* enc_g1   = (const float*)d_in[15];
  const float* enc_b1   = (const float*)d_in[16];
  const float* enc_g2   = (const float*)d_in[17];
  const float* enc_b2   = (const float*)d_in[18];
  const float* wp2      = (const float*)d_in[19];
  const float* bp2      = (const float*)d_in[20];
  const float* fs_w     = (const float*)d_in[21];
  const float* fs_b     = (const float*)d_in[22];
  const float* ft_w     = (const float*)d_in[23];
  const float* ft_b     = (const float*)d_in[24];
  const float* gru_w_ih = (const float*)d_in[25];
  const float* gru_w_hh = (const float*)d_in[26];
  const float* gru_b_ih = (const float*)d_in[27];
  const float* gru_b_hh = (const float*)d_in[28];
  const float* tp_w     = (const float*)d_in[29];
  const float* tp_b     = (const float*)d_in[30];
  const float* ltn_w    = (const float*)d_in[31];
  const float* ltn_b    = (const float*)d_in[32];
  const float* gat_wl   = (const float*)d_in[33];
  const float* gat_bl   = (const float*)d_in[34];
  const float* gat_wr   = (const float*)d_in[35];
  const float* gat_br   = (const float*)d_in[36];
  const float* gat_att  = (const float*)d_in[37];
  const float* gat_bias = (const float*)d_in[38];
  const float* gl_w     = (const float*)d_in[39];
  const float* gl_b     = (const float*)d_in[40];
  const int*   tctx     = (const int*)d_in[41];

  float* out = (float*)d_out;
  float* ws  = (float*)d_ws;
  // ws layout (floats)
  float* x_inst   = ws;                // 64*512
  float* x_lag    = ws + 32768;        // 64*512
  float* z2p      = ws + 65536;        // 512*128
  float* z2f      = ws + 131072;       // 512*128
  float* xl       = ws + 196608;       // 512*256
  float* xr       = ws + 327680;       // 512*256
  float* gi_table = ws + 458752;       // 100*384
  float* xemb     = ws + 497152;       // 512*256
  float* x0       = ws + 628224;       // 640*64
  float* x_enc    = ws + 669184;       // 640*64
  float* zn_ws    = ws + 710144;       // 512*512

  wp1_kernel<<<dim3(160), dim3(256), 0, stream>>>(X, wp1, bp1, x0);
  enc4_kernel<<<dim3(BAT), dim3(640), 0, stream>>>(
      x0, enc_in_w, enc_in_b, enc_out_w, enc_out_b,
      enc_l1_w, enc_l1_b, enc_l2_w, enc_l2_b,
      enc_g1, enc_b1, enc_g2, enc_b2, x_enc);
  wp2_kernel<<<dim3(128), dim3(256), 0, stream>>>(x_enc, wp2, bp2, x_inst, x_lag);
  adj_kernel<<<dim3(2 * NN), dim3(256), 0, stream>>>(
      x_inst, x_lag, es_now, es_lag, prior, out);
  gitab_kernel<<<dim3(100), dim3(384), 0, stream>>>(gru_w_ih, gru_b_ih, gi_table);
  flow_kernel<<<dim3(NN), dim3(128), 0, stream>>>(Z, fs_w, fs_b, ft_w, ft_b, z2p);
  gru_kernel2<<<dim3(NN), dim3(384), 0, stream>>>(
      tctx, gru_w_hh, gru_b_hh, gi_table, tp_w, tp_b, z2p, z2f);
  znA_kernel<<<dim3(512), dim3(256), 0, stream>>>(Z, z2f, ltn_w, ltn_b, zn_ws);
  znB_kernel<<<dim3(512), dim3(256), 0, stream>>>(
      zn_ws, gat_wl, gat_bl, gat_wr, gat_br, xl, xr);
  gat_kernel3<<<dim3(NN), dim3(256), 0, stream>>>(
      xl, xr, gat_att, gat_bias, xemb);
  glgemm_kernel<<<dim3(512), dim3(256), 0, stream>>>(
      xemb, gl_w, gl_b, out + 2 * NN * NN, out + 3 * NN * NN);
}